// Round 1
// baseline (831.460 us; speedup 1.0000x reference)
//
#include <hip/hip_runtime.h>
#include <math.h>

// Problem constants
static constexpr int Bv  = 2;
static constexpr int Ncam= 6;
static constexpr int Cch = 256;
static constexpr int Hh  = 56;
static constexpr int Ww  = 100;
static constexpr int Qn  = 900;
static constexpr int En  = 256;
static constexpr int NH  = 8;
static constexpr int HD  = 32;   // E / NH

// ---------------------------------------------------------------------------
// K1: ref3d = sigmoid(query_table @ ref_W + ref_b); project through lidar2img,
// produce per-(b,n,q) grid coords + combined mask. Also writes ref3d output.
// grid: Qn blocks, 64 threads (one wave).
// ---------------------------------------------------------------------------
__global__ void ref_grid_kernel(const float* __restrict__ qt,
                                const float* __restrict__ refW,
                                const float* __restrict__ refb,
                                const float* __restrict__ l2i,
                                float* __restrict__ gridbuf,
                                float* __restrict__ out_ref3d) {
    int q = blockIdx.x;
    int t = threadIdx.x;  // 0..63
    float s0 = 0.f, s1 = 0.f, s2 = 0.f;
    for (int i = t; i < En; i += 64) {
        float a = qt[q * En + i];
        s0 += a * refW[i * 3 + 0];
        s1 += a * refW[i * 3 + 1];
        s2 += a * refW[i * 3 + 2];
    }
    for (int off = 32; off > 0; off >>= 1) {
        s0 += __shfl_down(s0, off);
        s1 += __shfl_down(s1, off);
        s2 += __shfl_down(s2, off);
    }
    __shared__ float r3[3];
    if (t == 0) {
        float v0 = 1.f / (1.f + expf(-(s0 + refb[0])));
        float v1 = 1.f / (1.f + expf(-(s1 + refb[1])));
        float v2 = 1.f / (1.f + expf(-(s2 + refb[2])));
        r3[0] = v0; r3[1] = v1; r3[2] = v2;
        // ref3d identical for both batches
        out_ref3d[(size_t)(0 * Qn + q) * 3 + 0] = v0;
        out_ref3d[(size_t)(0 * Qn + q) * 3 + 1] = v1;
        out_ref3d[(size_t)(0 * Qn + q) * 3 + 2] = v2;
        out_ref3d[(size_t)(1 * Qn + q) * 3 + 0] = v0;
        out_ref3d[(size_t)(1 * Qn + q) * 3 + 1] = v1;
        out_ref3d[(size_t)(1 * Qn + q) * 3 + 2] = v2;
    }
    __syncthreads();
    if (t < Bv * Ncam) {
        int b = t / Ncam, n = t % Ncam;
        const float* M = l2i + (size_t)(b * Ncam + n) * 16;
        float p0 = M[0] * r3[0] + M[1] * r3[1] + M[2]  * r3[2] + M[3];
        float p1 = M[4] * r3[0] + M[5] * r3[1] + M[6]  * r3[2] + M[7];
        float z  = M[8] * r3[0] + M[9] * r3[1] + M[10] * r3[2] + M[11];
        float denom = fabsf(z) + 1e-5f;
        float px = p0 / denom, py = p1 / denom;
        float gx = px / (float)(Ww - 1) * 2.f - 1.f;
        float gy = py / (float)(Hh - 1) * 2.f - 1.f;
        bool zm = z > 1e-5f;
        bool valid = (gx > -1.f) && (gx < 1.f) && (gy > -1.f) && (gy < 1.f);
        float* g = gridbuf + ((size_t)(b * Ncam + n) * Qn + q) * 3;
        g[0] = gx; g[1] = gy; g[2] = (zm && valid) ? 1.f : 0.f;
    }
}

// ---------------------------------------------------------------------------
// K2: transpose feats (BN, C, H, W) -> (BN, H, W, C) so channel gathers are
// contiguous. block 32x8, tile 32(c) x 32(w) per (m,h).
// ---------------------------------------------------------------------------
__global__ void transpose_kernel(const float* __restrict__ in,
                                 float* __restrict__ outp) {
    __shared__ float tile[32][33];
    int mh = blockIdx.z;
    int m = mh / Hh, h = mh % Hh;
    int w0 = blockIdx.x * 32, c0 = blockIdx.y * 32;
    int tx = threadIdx.x, ty = threadIdx.y;  // 32, 8
    for (int i = 0; i < 32; i += 8) {
        int c = c0 + ty + i, w = w0 + tx;
        if (w < Ww)
            tile[ty + i][tx] = in[(((size_t)m * Cch + c) * Hh + h) * Ww + w];
    }
    __syncthreads();
    for (int i = 0; i < 32; i += 8) {
        int w = w0 + ty + i, c = c0 + tx;
        if (w < Ww)
            outp[(((size_t)m * Hh + h) * Ww + w) * Cch + c] = tile[tx][ty + i];
    }
}

// ---------------------------------------------------------------------------
// K3: bilinear sample + masked mean over cameras + add query embedding.
// One block per (b,q), 256 threads = channels. featsT layout (m,H,W,C).
// ---------------------------------------------------------------------------
__device__ __forceinline__ float corner_val(const float* __restrict__ base,
                                            int xi, int yi, int c) {
    if (xi < 0 || xi >= Ww || yi < 0 || yi >= Hh) return 0.f;
    return base[((size_t)yi * Ww + xi) * Cch + c];
}

__global__ void sample_kernel(const float* __restrict__ featsT,
                              const float* __restrict__ gridbuf,
                              const float* __restrict__ qt,
                              float* __restrict__ xbuf) {
    int bq = blockIdx.x;
    int b = bq / Qn, q = bq % Qn;
    int c = threadIdx.x;
    float acc = 0.f, cnt = 0.f;
    for (int n = 0; n < Ncam; n++) {
        const float* g = gridbuf + ((size_t)(b * Ncam + n) * Qn + q) * 3;
        float gx = g[0], gy = g[1], msk = g[2];
        if (msk > 0.5f) {
            cnt += 1.f;
            float x = ((gx + 1.f) * (float)Ww - 1.f) * 0.5f;
            float y = ((gy + 1.f) * (float)Hh - 1.f) * 0.5f;
            float x0f = floorf(x), y0f = floorf(y);
            int x0 = (int)x0f, y0 = (int)y0f;
            float wx1 = x - x0f, wx0 = 1.f - wx1;
            float wy1 = y - y0f, wy0 = 1.f - wy1;
            int m = b * Ncam + n;
            const float* base = featsT + (size_t)m * Hh * Ww * Cch;
            acc += corner_val(base, x0,     y0,     c) * (wx0 * wy0);
            acc += corner_val(base, x0 + 1, y0,     c) * (wx1 * wy0);
            acc += corner_val(base, x0,     y0 + 1, c) * (wx0 * wy1);
            acc += corner_val(base, x0 + 1, y0 + 1, c) * (wx1 * wy1);
        }
    }
    float tgt = acc / fmaxf(cnt, 1.f);
    xbuf[(size_t)bq * En + c] = qt[q * En + c] + tgt;
}

// ---------------------------------------------------------------------------
// K4: generic fp32 GEMM  C[M,N] = A[M,K] @ W[K,N] + bias[N]
// 64x64 tile, BK=16, 256 threads, 4x4 per thread.
// ---------------------------------------------------------------------------
__global__ void gemm_bias_kernel(const float* __restrict__ A,
                                 const float* __restrict__ Wm,
                                 const float* __restrict__ bias,
                                 float* __restrict__ Cout,
                                 int M, int K, int Nn) {
    __shared__ float As[16][65];
    __shared__ float Bs[16][65];
    int t = threadIdx.x;
    int m0 = blockIdx.x * 64, n0 = blockIdx.y * 64;
    int tx = t % 16, ty = t / 16;
    float acc[4][4] = {};
    for (int k0 = 0; k0 < K; k0 += 16) {
        {
            int kk = t % 16, mb = t / 16;
            for (int i = 0; i < 4; i++) {
                int mm = mb + 16 * i;
                int mg = m0 + mm;
                As[kk][mm] = (mg < M) ? A[(size_t)mg * K + k0 + kk] : 0.f;
            }
        }
        {
            int nn = t % 64, kb = t / 64;
            for (int i = 0; i < 4; i++) {
                int kk = kb + 4 * i;
                Bs[kk][nn] = Wm[(size_t)(k0 + kk) * Nn + n0 + nn];
            }
        }
        __syncthreads();
        for (int kk = 0; kk < 16; kk++) {
            float a[4], bb[4];
            #pragma unroll
            for (int i = 0; i < 4; i++) a[i] = As[kk][ty * 4 + i];
            #pragma unroll
            for (int j = 0; j < 4; j++) bb[j] = Bs[kk][tx * 4 + j];
            #pragma unroll
            for (int i = 0; i < 4; i++)
                #pragma unroll
                for (int j = 0; j < 4; j++) acc[i][j] += a[i] * bb[j];
        }
        __syncthreads();
    }
    for (int i = 0; i < 4; i++) {
        int m = m0 + ty * 4 + i;
        if (m >= M) continue;
        for (int j = 0; j < 4; j++) {
            int n = n0 + tx * 4 + j;
            Cout[(size_t)m * Nn + n] = acc[i][j] + bias[n];
        }
    }
}

// ---------------------------------------------------------------------------
// K5: attention scores S[bh, m, n] = (q . k)/sqrt(hd). 64x64 tile, d=32.
// ---------------------------------------------------------------------------
__global__ void scores_kernel(const float* __restrict__ qbuf,
                              const float* __restrict__ kbuf,
                              float* __restrict__ S) {
    __shared__ float Qs[64][33];
    __shared__ float Ks[64][33];
    int bh = blockIdx.z;
    int b = bh / NH, h = bh % NH;
    int m0 = blockIdx.x * 64, n0 = blockIdx.y * 64;
    int t = threadIdx.x;
    {
        int d = t % 32, rb = t / 32;  // 8 rows per pass
        for (int i = 0; i < 8; i++) {
            int r = rb + i * 8;
            int mg = m0 + r, ng = n0 + r;
            Qs[r][d] = (mg < Qn) ? qbuf[((size_t)b * Qn + mg) * En + h * HD + d] : 0.f;
            Ks[r][d] = (ng < Qn) ? kbuf[((size_t)b * Qn + ng) * En + h * HD + d] : 0.f;
        }
    }
    __syncthreads();
    int tx = t % 16, ty = t / 16;
    float acc[4][4] = {};
    for (int d = 0; d < 32; d++) {
        float a[4], bb[4];
        #pragma unroll
        for (int i = 0; i < 4; i++) a[i] = Qs[ty * 4 + i][d];
        #pragma unroll
        for (int j = 0; j < 4; j++) bb[j] = Ks[tx * 4 + j][d];
        #pragma unroll
        for (int i = 0; i < 4; i++)
            #pragma unroll
            for (int j = 0; j < 4; j++) acc[i][j] += a[i] * bb[j];
    }
    const float scale = 0.17677669529663687f;  // 1/sqrt(32)
    for (int i = 0; i < 4; i++) {
        int m = m0 + ty * 4 + i;
        if (m >= Qn) continue;
        for (int j = 0; j < 4; j++) {
            int n = n0 + tx * 4 + j;
            if (n < Qn)
                S[((size_t)bh * Qn + m) * Qn + n] = acc[i][j] * scale;
        }
    }
}

// ---------------------------------------------------------------------------
// K6: row softmax over 900 entries. one block (256 thr) per row.
// ---------------------------------------------------------------------------
__global__ void softmax_kernel(float* __restrict__ S) {
    size_t row = blockIdx.x;
    float* p = S + row * Qn;
    int t = threadIdx.x;
    __shared__ float red[256];
    float v[4];
    float mx = -1e30f;
    for (int j = 0; j < 4; j++) {
        int i = t + j * 256;
        v[j] = (i < Qn) ? p[i] : -1e30f;
        mx = fmaxf(mx, v[j]);
    }
    red[t] = mx; __syncthreads();
    for (int s = 128; s > 0; s >>= 1) {
        if (t < s) red[t] = fmaxf(red[t], red[t + s]);
        __syncthreads();
    }
    mx = red[0]; __syncthreads();
    float sum = 0.f;
    for (int j = 0; j < 4; j++) {
        int i = t + j * 256;
        v[j] = (i < Qn) ? expf(v[j] - mx) : 0.f;
        sum += v[j];
    }
    red[t] = sum; __syncthreads();
    for (int s = 128; s > 0; s >>= 1) {
        if (t < s) red[t] += red[t + s];
        __syncthreads();
    }
    float inv = 1.f / red[0];
    for (int j = 0; j < 4; j++) {
        int i = t + j * 256;
        if (i < Qn) p[i] = v[j] * inv;
    }
}

// ---------------------------------------------------------------------------
// K7: O[bh, m, d] = sum_k P[bh,m,k] V[b,k,h,d]. 32(m)x32(d) tile, k-chunk 64.
// ---------------------------------------------------------------------------
__global__ void pv_kernel(const float* __restrict__ S,
                          const float* __restrict__ vbuf,
                          float* __restrict__ Obuf) {
    __shared__ float Ps[32][65];
    __shared__ float Vs[64][33];
    int bh = blockIdx.y;
    int b = bh / NH, h = bh % NH;
    int m0 = blockIdx.x * 32;
    int t = threadIdx.x;
    int tx = t % 32, ty = t / 32;  // ty 0..7
    float acc[4] = {0.f, 0.f, 0.f, 0.f};
    const float* Sp = S + (size_t)bh * Qn * Qn;
    for (int k0 = 0; k0 < Qn; k0 += 64) {
        {
            int kk = t % 64, mb = t / 64;  // mb 0..3
            for (int i = 0; i < 8; i++) {
                int m = mb + i * 4;
                int kg = k0 + kk, mg = m0 + m;
                Ps[m][kk] = (kg < Qn && mg < Qn) ? Sp[(size_t)mg * Qn + kg] : 0.f;
            }
        }
        {
            int d = t % 32, kb = t / 32;  // kb 0..7
            for (int i = 0; i < 8; i++) {
                int k = kb + i * 8;
                int kg = k0 + k;
                Vs[k][d] = (kg < Qn) ? vbuf[((size_t)b * Qn + kg) * En + h * HD + d] : 0.f;
            }
        }
        __syncthreads();
        for (int kk = 0; kk < 64; kk++) {
            float vv = Vs[kk][tx];
            #pragma unroll
            for (int i = 0; i < 4; i++) acc[i] += Ps[ty + i * 8][kk] * vv;
        }
        __syncthreads();
    }
    for (int i = 0; i < 4; i++) {
        int m = m0 + ty + i * 8;
        if (m < Qn) Obuf[((size_t)bh * Qn + m) * HD + tx] = acc[i];
    }
}

// ---------------------------------------------------------------------------
// K8: x2 = o@Wo+bo ; LN ; out = y@box_W+box_b. One block per (b,q).
// ---------------------------------------------------------------------------
__global__ void final_kernel(const float* __restrict__ Obuf,
                             const float* __restrict__ Wo,
                             const float* __restrict__ bo,
                             const float* __restrict__ ln_g,
                             const float* __restrict__ ln_b,
                             const float* __restrict__ boxW,
                             const float* __restrict__ boxb,
                             float* __restrict__ outp) {
    __shared__ float orow[En];
    __shared__ float red[256];
    __shared__ float yrow[En];
    int bq = blockIdx.x;
    int b = bq / Qn, q = bq % Qn;
    int t = threadIdx.x;
    int h = t / HD, d = t % HD;
    orow[t] = Obuf[((size_t)(b * NH + h) * Qn + q) * HD + d];
    __syncthreads();
    float acc = bo[t];
    for (int k = 0; k < En; k++) acc += orow[k] * Wo[(size_t)k * En + t];
    // layernorm
    red[t] = acc; __syncthreads();
    for (int s = 128; s > 0; s >>= 1) {
        if (t < s) red[t] += red[t + s];
        __syncthreads();
    }
    float mu = red[0] / (float)En;
    __syncthreads();
    float dx = acc - mu;
    red[t] = dx * dx; __syncthreads();
    for (int s = 128; s > 0; s >>= 1) {
        if (t < s) red[t] += red[t + s];
        __syncthreads();
    }
    float var = red[0] / (float)En;
    float y = dx * rsqrtf(var + 1e-5f) * ln_g[t] + ln_b[t];
    yrow[t] = y;
    __syncthreads();
    if (t < 10) {
        float o = boxb[t];
        for (int k = 0; k < En; k++) o += yrow[k] * boxW[(size_t)k * 10 + t];
        outp[(size_t)bq * 10 + t] = o;
    }
}

// ---------------------------------------------------------------------------
extern "C" void kernel_launch(void* const* d_in, const int* in_sizes, int n_in,
                              void* d_out, int out_size, void* d_ws, size_t ws_size,
                              hipStream_t stream) {
    const float* image_features = (const float*)d_in[0];
    const float* lidar2img      = (const float*)d_in[1];
    const float* query_table    = (const float*)d_in[2];
    const float* ref_W          = (const float*)d_in[3];
    const float* ref_b          = (const float*)d_in[4];
    const float* Wq             = (const float*)d_in[5];
    const float* bq             = (const float*)d_in[6];
    const float* Wk             = (const float*)d_in[7];
    const float* bk             = (const float*)d_in[8];
    const float* Wv             = (const float*)d_in[9];
    const float* bv             = (const float*)d_in[10];
    const float* Wo             = (const float*)d_in[11];
    const float* bo             = (const float*)d_in[12];
    const float* ln_g           = (const float*)d_in[13];
    const float* ln_b           = (const float*)d_in[14];
    const float* box_W          = (const float*)d_in[15];
    const float* box_b          = (const float*)d_in[16];
    float* out = (float*)d_out;

    float* ws = (float*)d_ws;
    size_t off = 0;
    float* gridbuf = ws + off; off += (size_t)Bv * Ncam * Qn * 3;
    float* featsT  = ws + off; off += (size_t)Bv * Ncam * Hh * Ww * Cch;
    float* xbuf    = ws + off; off += (size_t)Bv * Qn * En;
    float* qbuf    = ws + off; off += (size_t)Bv * Qn * En;
    float* kbuf    = ws + off; off += (size_t)Bv * Qn * En;
    float* vbuf    = ws + off; off += (size_t)Bv * Qn * En;
    float* Obuf    = ws + off; off += (size_t)Bv * Qn * En;
    float* Sbuf    = ws + off; off += (size_t)Bv * NH * Qn * Qn;

    float* out_ref3d = out + (size_t)Bv * Qn * 10;  // second tuple element

    // K1: ref points + projection grid
    hipLaunchKernelGGL(ref_grid_kernel, dim3(Qn), dim3(64), 0, stream,
                       query_table, ref_W, ref_b, lidar2img, gridbuf, out_ref3d);

    // K2: transpose features to channel-last
    hipLaunchKernelGGL(transpose_kernel, dim3(4, 8, Bv * Ncam * Hh), dim3(32, 8),
                       0, stream, image_features, featsT);

    // K3: bilinear sample + masked mean + add query embedding
    hipLaunchKernelGGL(sample_kernel, dim3(Bv * Qn), dim3(256), 0, stream,
                       featsT, gridbuf, query_table, xbuf);

    // K4: q/k/v projections
    int M = Bv * Qn;
    dim3 ggrid((M + 63) / 64, En / 64);
    hipLaunchKernelGGL(gemm_bias_kernel, ggrid, dim3(256), 0, stream,
                       xbuf, Wq, bq, qbuf, M, En, En);
    hipLaunchKernelGGL(gemm_bias_kernel, ggrid, dim3(256), 0, stream,
                       xbuf, Wk, bk, kbuf, M, En, En);
    hipLaunchKernelGGL(gemm_bias_kernel, ggrid, dim3(256), 0, stream,
                       xbuf, Wv, bv, vbuf, M, En, En);

    // K5: scores
    hipLaunchKernelGGL(scores_kernel, dim3((Qn + 63) / 64, (Qn + 63) / 64, Bv * NH),
                       dim3(256), 0, stream, qbuf, kbuf, Sbuf);

    // K6: softmax
    hipLaunchKernelGGL(softmax_kernel, dim3(Bv * NH * Qn), dim3(256), 0, stream, Sbuf);

    // K7: P @ V
    hipLaunchKernelGGL(pv_kernel, dim3((Qn + 31) / 32, Bv * NH), dim3(256), 0, stream,
                       Sbuf, vbuf, Obuf);

    // K8: output projection + LN + box head
    hipLaunchKernelGGL(final_kernel, dim3(Bv * Qn), dim3(256), 0, stream,
                       Obuf, Wo, bo, ln_g, ln_b, box_W, box_b, out);
}

// Round 2
// 355.452 us; speedup vs baseline: 2.3392x; 2.3392x over previous
//
#include <hip/hip_runtime.h>
#include <math.h>

// Problem constants
static constexpr int Bv  = 2;
static constexpr int Ncam= 6;
static constexpr int Cch = 256;
static constexpr int Hh  = 56;
static constexpr int Ww  = 100;
static constexpr int Qn  = 900;
static constexpr int En  = 256;
static constexpr int NH  = 8;
static constexpr int HD  = 32;   // E / NH

// ---------------------------------------------------------------------------
// K1: ref3d = sigmoid(query_table @ ref_W + ref_b); project through lidar2img,
// produce per-(b,n,q) grid coords + combined mask. Also writes ref3d output.
// ---------------------------------------------------------------------------
__global__ void ref_grid_kernel(const float* __restrict__ qt,
                                const float* __restrict__ refW,
                                const float* __restrict__ refb,
                                const float* __restrict__ l2i,
                                float* __restrict__ gridbuf,
                                float* __restrict__ out_ref3d) {
    int q = blockIdx.x;
    int t = threadIdx.x;  // 0..63
    float s0 = 0.f, s1 = 0.f, s2 = 0.f;
    for (int i = t; i < En; i += 64) {
        float a = qt[q * En + i];
        s0 += a * refW[i * 3 + 0];
        s1 += a * refW[i * 3 + 1];
        s2 += a * refW[i * 3 + 2];
    }
    for (int off = 32; off > 0; off >>= 1) {
        s0 += __shfl_down(s0, off);
        s1 += __shfl_down(s1, off);
        s2 += __shfl_down(s2, off);
    }
    __shared__ float r3[3];
    if (t == 0) {
        float v0 = 1.f / (1.f + expf(-(s0 + refb[0])));
        float v1 = 1.f / (1.f + expf(-(s1 + refb[1])));
        float v2 = 1.f / (1.f + expf(-(s2 + refb[2])));
        r3[0] = v0; r3[1] = v1; r3[2] = v2;
        out_ref3d[(size_t)(0 * Qn + q) * 3 + 0] = v0;
        out_ref3d[(size_t)(0 * Qn + q) * 3 + 1] = v1;
        out_ref3d[(size_t)(0 * Qn + q) * 3 + 2] = v2;
        out_ref3d[(size_t)(1 * Qn + q) * 3 + 0] = v0;
        out_ref3d[(size_t)(1 * Qn + q) * 3 + 1] = v1;
        out_ref3d[(size_t)(1 * Qn + q) * 3 + 2] = v2;
    }
    __syncthreads();
    if (t < Bv * Ncam) {
        int b = t / Ncam, n = t % Ncam;
        const float* M = l2i + (size_t)(b * Ncam + n) * 16;
        float p0 = M[0] * r3[0] + M[1] * r3[1] + M[2]  * r3[2] + M[3];
        float p1 = M[4] * r3[0] + M[5] * r3[1] + M[6]  * r3[2] + M[7];
        float z  = M[8] * r3[0] + M[9] * r3[1] + M[10] * r3[2] + M[11];
        float denom = fabsf(z) + 1e-5f;
        float px = p0 / denom, py = p1 / denom;
        float gx = px / (float)(Ww - 1) * 2.f - 1.f;
        float gy = py / (float)(Hh - 1) * 2.f - 1.f;
        bool zm = z > 1e-5f;
        bool valid = (gx > -1.f) && (gx < 1.f) && (gy > -1.f) && (gy < 1.f);
        float* g = gridbuf + ((size_t)(b * Ncam + n) * Qn + q) * 3;
        g[0] = gx; g[1] = gy; g[2] = (zm && valid) ? 1.f : 0.f;
    }
}

// ---------------------------------------------------------------------------
// K2: transpose feats (BN, C, H, W) -> (BN, H, W, C).
// ---------------------------------------------------------------------------
__global__ void transpose_kernel(const float* __restrict__ in,
                                 float* __restrict__ outp) {
    __shared__ float tile[32][33];
    int mh = blockIdx.z;
    int m = mh / Hh, h = mh % Hh;
    int w0 = blockIdx.x * 32, c0 = blockIdx.y * 32;
    int tx = threadIdx.x, ty = threadIdx.y;  // 32, 8
    for (int i = 0; i < 32; i += 8) {
        int c = c0 + ty + i, w = w0 + tx;
        if (w < Ww)
            tile[ty + i][tx] = in[(((size_t)m * Cch + c) * Hh + h) * Ww + w];
    }
    __syncthreads();
    for (int i = 0; i < 32; i += 8) {
        int w = w0 + ty + i, c = c0 + tx;
        if (w < Ww)
            outp[(((size_t)m * Hh + h) * Ww + w) * Cch + c] = tile[tx][ty + i];
    }
}

// ---------------------------------------------------------------------------
// K3: bilinear sample + masked mean + add query embedding.
// ---------------------------------------------------------------------------
__device__ __forceinline__ float corner_val(const float* __restrict__ base,
                                            int xi, int yi, int c) {
    if (xi < 0 || xi >= Ww || yi < 0 || yi >= Hh) return 0.f;
    return base[((size_t)yi * Ww + xi) * Cch + c];
}

__global__ void sample_kernel(const float* __restrict__ featsT,
                              const float* __restrict__ gridbuf,
                              const float* __restrict__ qt,
                              float* __restrict__ xbuf) {
    int bq = blockIdx.x;
    int b = bq / Qn, q = bq % Qn;
    int c = threadIdx.x;
    float acc = 0.f, cnt = 0.f;
    for (int n = 0; n < Ncam; n++) {
        const float* g = gridbuf + ((size_t)(b * Ncam + n) * Qn + q) * 3;
        float gx = g[0], gy = g[1], msk = g[2];
        if (msk > 0.5f) {
            cnt += 1.f;
            float x = ((gx + 1.f) * (float)Ww - 1.f) * 0.5f;
            float y = ((gy + 1.f) * (float)Hh - 1.f) * 0.5f;
            float x0f = floorf(x), y0f = floorf(y);
            int x0 = (int)x0f, y0 = (int)y0f;
            float wx1 = x - x0f, wx0 = 1.f - wx1;
            float wy1 = y - y0f, wy0 = 1.f - wy1;
            int m = b * Ncam + n;
            const float* base = featsT + (size_t)m * Hh * Ww * Cch;
            acc += corner_val(base, x0,     y0,     c) * (wx0 * wy0);
            acc += corner_val(base, x0 + 1, y0,     c) * (wx1 * wy0);
            acc += corner_val(base, x0,     y0 + 1, c) * (wx0 * wy1);
            acc += corner_val(base, x0 + 1, y0 + 1, c) * (wx1 * wy1);
        }
    }
    float tgt = acc / fmaxf(cnt, 1.f);
    xbuf[(size_t)bq * En + c] = qt[q * En + c] + tgt;
}

// ---------------------------------------------------------------------------
// K4: generic fp32 GEMM  C[M,N] = A[M,K] @ W[K,N] + bias[N]
// ---------------------------------------------------------------------------
__device__ __forceinline__ void gemm_body(const float* __restrict__ A,
                                          const float* __restrict__ Wm,
                                          const float* __restrict__ bias,
                                          float* __restrict__ Cout,
                                          int M, int K, int Nn,
                                          int m0, int n0) {
    __shared__ float As[16][65];
    __shared__ float Bs[16][65];
    int t = threadIdx.x;
    int tx = t % 16, ty = t / 16;
    float acc[4][4] = {};
    for (int k0 = 0; k0 < K; k0 += 16) {
        {
            int kk = t % 16, mb = t / 16;
            for (int i = 0; i < 4; i++) {
                int mm = mb + 16 * i;
                int mg = m0 + mm;
                As[kk][mm] = (mg < M) ? A[(size_t)mg * K + k0 + kk] : 0.f;
            }
        }
        {
            int nn = t % 64, kb = t / 64;
            for (int i = 0; i < 4; i++) {
                int kk = kb + 4 * i;
                Bs[kk][nn] = Wm[(size_t)(k0 + kk) * Nn + n0 + nn];
            }
        }
        __syncthreads();
        for (int kk = 0; kk < 16; kk++) {
            float a[4], bb[4];
            #pragma unroll
            for (int i = 0; i < 4; i++) a[i] = As[kk][ty * 4 + i];
            #pragma unroll
            for (int j = 0; j < 4; j++) bb[j] = Bs[kk][tx * 4 + j];
            #pragma unroll
            for (int i = 0; i < 4; i++)
                #pragma unroll
                for (int j = 0; j < 4; j++) acc[i][j] += a[i] * bb[j];
        }
        __syncthreads();
    }
    for (int i = 0; i < 4; i++) {
        int m = m0 + ty * 4 + i;
        if (m >= M) continue;
        for (int j = 0; j < 4; j++) {
            int n = n0 + tx * 4 + j;
            Cout[(size_t)m * Nn + n] = acc[i][j] + bias[n];
        }
    }
}

__global__ void gemm_bias_kernel(const float* __restrict__ A,
                                 const float* __restrict__ Wm,
                                 const float* __restrict__ bias,
                                 float* __restrict__ Cout,
                                 int M, int K, int Nn) {
    gemm_body(A, Wm, bias, Cout, M, K, Nn, blockIdx.x * 64, blockIdx.y * 64);
}

// One launch for q/k/v projections (blockIdx.z selects which).
__global__ void qkv_gemm_kernel(const float* __restrict__ A,
                                const float* __restrict__ Wq, const float* __restrict__ bq,
                                const float* __restrict__ Wk, const float* __restrict__ bk,
                                const float* __restrict__ Wv, const float* __restrict__ bv,
                                float* __restrict__ qo, float* __restrict__ ko,
                                float* __restrict__ vo, int M) {
    const float* Wm; const float* bias; float* Cout;
    if (blockIdx.z == 0)      { Wm = Wq; bias = bq; Cout = qo; }
    else if (blockIdx.z == 1) { Wm = Wk; bias = bk; Cout = ko; }
    else                      { Wm = Wv; bias = bv; Cout = vo; }
    gemm_body(A, Wm, bias, Cout, M, En, En, blockIdx.x * 64, blockIdx.y * 64);
}

// ---------------------------------------------------------------------------
// K5: fused flash attention. One block = (bh, 32 q-rows). 256 threads.
// K/V tiles of 64 staged in LDS; online softmax; O accumulated in registers.
// Writes O directly in (b, q, E) layout so the Wo GEMM consumes it as-is.
// ---------------------------------------------------------------------------
static constexpr int TQ = 32;
static constexpr int TK = 64;

__global__ void flash_attn_kernel(const float* __restrict__ qbuf,
                                  const float* __restrict__ kbuf,
                                  const float* __restrict__ vbuf,
                                  float* __restrict__ obuf) {
    __shared__ float Qs[TQ][HD + 1];
    __shared__ float Ks[TK][HD + 1];
    __shared__ float Vs[TK][HD + 1];
    __shared__ float Ss[TQ][TK + 1];
    __shared__ float pmax[TQ][8];
    __shared__ float psum[TQ][8];
    __shared__ float mrow[TQ], lrow[TQ], arow[TQ];

    int bh = blockIdx.y;
    int b = bh / NH, h = bh % NH;
    int m0 = blockIdx.x * TQ;
    int t = threadIdx.x;

    {   // load Q tile (32 x 32)
        int d = t % HD, r = t / HD;  // r 0..7
        for (int i = 0; i < 4; i++) {
            int m = r + i * 8;
            int mg = m0 + m;
            Qs[m][d] = (mg < Qn) ? qbuf[((size_t)b * Qn + mg) * En + h * HD + d] : 0.f;
        }
    }
    if (t < TQ) { mrow[t] = -1e30f; lrow[t] = 0.f; }
    float oacc[4] = {0.f, 0.f, 0.f, 0.f};  // d = t%32, m rows t/32 + 8*i
    __syncthreads();

    const float scale = 0.17677669529663687f;  // 1/sqrt(32)
    int ms = t % TQ, nc = t / TQ;              // S-compute mapping
    int dd = t % HD, mg_ = t / HD;             // PV mapping

    for (int k0 = 0; k0 < Qn; k0 += TK) {
        {   // load K,V tiles (64 x 32)
            int d = t % HD, r = t / HD;
            for (int i = 0; i < 8; i++) {
                int n = r + i * 8;
                int ng = k0 + n;
                float kv = 0.f, vv = 0.f;
                if (ng < Qn) {
                    kv = kbuf[((size_t)b * Qn + ng) * En + h * HD + d];
                    vv = vbuf[((size_t)b * Qn + ng) * En + h * HD + d];
                }
                Ks[n][d] = kv; Vs[n][d] = vv;
            }
        }
        __syncthreads();
        // S tile: thread covers row ms, cols nc*8..nc*8+7
        float sv[8];
        float lmax = -1e30f;
        #pragma unroll
        for (int j = 0; j < 8; j++) {
            int n = nc * 8 + j;
            float acc = 0.f;
            #pragma unroll
            for (int k = 0; k < HD; k++)
                acc += Qs[ms][k] * Ks[n][k];
            acc *= scale;
            sv[j] = (k0 + n < Qn) ? acc : -1e30f;
            lmax = fmaxf(lmax, sv[j]);
        }
        pmax[ms][nc] = lmax;
        __syncthreads();
        if (t < TQ) {
            float m_new = mrow[t];
            #pragma unroll
            for (int c = 0; c < 8; c++) m_new = fmaxf(m_new, pmax[t][c]);
            arow[t] = expf(mrow[t] - m_new);  // first tile: exp(-inf)=0, lrow=0
            mrow[t] = m_new;
        }
        __syncthreads();
        {   // exponentiate, write P, partial sums
            float mr = mrow[ms];
            float ps = 0.f;
            #pragma unroll
            for (int j = 0; j < 8; j++) {
                int n = nc * 8 + j;
                float p = expf(sv[j] - mr);
                Ss[ms][n] = p;
                ps += p;
            }
            psum[ms][nc] = ps;
        }
        __syncthreads();
        if (t < TQ) {
            float s = 0.f;
            #pragma unroll
            for (int c = 0; c < 8; c++) s += psum[t][c];
            lrow[t] = lrow[t] * arow[t] + s;
        }
        // PV accumulate with rescale
        #pragma unroll
        for (int i = 0; i < 4; i++) {
            int m = mg_ + i * 8;
            float al = arow[m];
            float acc = 0.f;
            #pragma unroll
            for (int k = 0; k < TK; k++)
                acc += Ss[m][k] * Vs[k][dd];
            oacc[i] = oacc[i] * al + acc;
        }
        __syncthreads();
    }
    for (int i = 0; i < 4; i++) {
        int m = mg_ + i * 8;
        int mg = m0 + m;
        if (mg < Qn)
            obuf[((size_t)b * Qn + mg) * En + h * HD + dd] = oacc[i] / lrow[m];
    }
}

// ---------------------------------------------------------------------------
// K6: LN + box head. One block per (b,q), 256 threads.
// ---------------------------------------------------------------------------
__global__ void ln_box_kernel(const float* __restrict__ x2,
                              const float* __restrict__ ln_g,
                              const float* __restrict__ ln_b,
                              const float* __restrict__ boxW,
                              const float* __restrict__ boxb,
                              float* __restrict__ outp) {
    __shared__ float red[256];
    __shared__ float yrow[En];
    __shared__ float pbox[16][10];
    int bq = blockIdx.x;
    int t = threadIdx.x;
    float acc = x2[(size_t)bq * En + t];
    red[t] = acc; __syncthreads();
    for (int s = 128; s > 0; s >>= 1) {
        if (t < s) red[t] += red[t + s];
        __syncthreads();
    }
    float mu = red[0] / (float)En;
    __syncthreads();
    float dx = acc - mu;
    red[t] = dx * dx; __syncthreads();
    for (int s = 128; s > 0; s >>= 1) {
        if (t < s) red[t] += red[t + s];
        __syncthreads();
    }
    float var = red[0] / (float)En;
    float y = dx * rsqrtf(var + 1e-5f) * ln_g[t] + ln_b[t];
    yrow[t] = y;
    __syncthreads();
    // box head: 160 threads, out j = t%10, chunk = t/10 (16 chunks of 16)
    if (t < 160) {
        int j = t % 10, ch = t / 10;
        float p = 0.f;
        for (int k = ch * 16; k < ch * 16 + 16; k++)
            p += yrow[k] * boxW[(size_t)k * 10 + j];
        pbox[ch][j] = p;
    }
    __syncthreads();
    if (t < 10) {
        float o = boxb[t];
        for (int ch = 0; ch < 16; ch++) o += pbox[ch][t];
        outp[(size_t)bq * 10 + t] = o;
    }
}

// ---------------------------------------------------------------------------
extern "C" void kernel_launch(void* const* d_in, const int* in_sizes, int n_in,
                              void* d_out, int out_size, void* d_ws, size_t ws_size,
                              hipStream_t stream) {
    const float* image_features = (const float*)d_in[0];
    const float* lidar2img      = (const float*)d_in[1];
    const float* query_table    = (const float*)d_in[2];
    const float* ref_W          = (const float*)d_in[3];
    const float* ref_b          = (const float*)d_in[4];
    const float* Wq             = (const float*)d_in[5];
    const float* bq             = (const float*)d_in[6];
    const float* Wk             = (const float*)d_in[7];
    const float* bk             = (const float*)d_in[8];
    const float* Wv             = (const float*)d_in[9];
    const float* bv             = (const float*)d_in[10];
    const float* Wo             = (const float*)d_in[11];
    const float* bo             = (const float*)d_in[12];
    const float* ln_g           = (const float*)d_in[13];
    const float* ln_b           = (const float*)d_in[14];
    const float* box_W          = (const float*)d_in[15];
    const float* box_b          = (const float*)d_in[16];
    float* out = (float*)d_out;

    float* ws = (float*)d_ws;
    size_t off = 0;
    float* gridbuf = ws + off; off += (size_t)Bv * Ncam * Qn * 3;
    float* featsT  = ws + off; off += (size_t)Bv * Ncam * Hh * Ww * Cch;
    float* xbuf    = ws + off; off += (size_t)Bv * Qn * En;
    float* qbuf    = ws + off; off += (size_t)Bv * Qn * En;
    float* kbuf    = ws + off; off += (size_t)Bv * Qn * En;
    float* vbuf    = ws + off; off += (size_t)Bv * Qn * En;
    float* Obuf    = ws + off; off += (size_t)Bv * Qn * En;   // (b,q,E)
    float* x2buf   = ws + off; off += (size_t)Bv * Qn * En;

    float* out_ref3d = out + (size_t)Bv * Qn * 10;

    // K1: ref points + projection grid
    hipLaunchKernelGGL(ref_grid_kernel, dim3(Qn), dim3(64), 0, stream,
                       query_table, ref_W, ref_b, lidar2img, gridbuf, out_ref3d);

    // K2: transpose features to channel-last
    hipLaunchKernelGGL(transpose_kernel, dim3(4, 8, Bv * Ncam * Hh), dim3(32, 8),
                       0, stream, image_features, featsT);

    // K3: bilinear sample + masked mean + add query embedding
    hipLaunchKernelGGL(sample_kernel, dim3(Bv * Qn), dim3(256), 0, stream,
                       featsT, gridbuf, query_table, xbuf);

    // K4: q/k/v projections (single launch, z = 3)
    int M = Bv * Qn;
    hipLaunchKernelGGL(qkv_gemm_kernel, dim3((M + 63) / 64, En / 64, 3), dim3(256),
                       0, stream, xbuf, Wq, bq, Wk, bk, Wv, bv, qbuf, kbuf, vbuf, M);

    // K5: fused attention
    hipLaunchKernelGGL(flash_attn_kernel, dim3((Qn + TQ - 1) / TQ, Bv * NH),
                       dim3(256), 0, stream, qbuf, kbuf, vbuf, Obuf);

    // K6: o @ Wo + bo
    hipLaunchKernelGGL(gemm_bias_kernel, dim3((M + 63) / 64, En / 64), dim3(256),
                       0, stream, Obuf, Wo, bo, x2buf, M, En, En);

    // K7: LN + box head
    hipLaunchKernelGGL(ln_box_kernel, dim3(Bv * Qn), dim3(256), 0, stream,
                       x2buf, ln_g, ln_b, box_W, box_b, out);
}

// Round 3
// 270.429 us; speedup vs baseline: 3.0746x; 1.3144x over previous
//
#include <hip/hip_runtime.h>
#include <math.h>

// Problem constants
static constexpr int Bv  = 2;
static constexpr int Ncam= 6;
static constexpr int Cch = 256;
static constexpr int Hh  = 56;
static constexpr int Ww  = 100;
static constexpr int Qn  = 900;
static constexpr int En  = 256;
static constexpr int NH  = 8;
static constexpr int HD  = 32;   // E / NH

typedef short bf16x8 __attribute__((ext_vector_type(8)));
typedef float f32x4  __attribute__((ext_vector_type(4)));

__device__ __forceinline__ unsigned short f2bf(float f) {
    union { float f; unsigned int u; } x; x.f = f;
    unsigned int r = x.u + 0x7fffu + ((x.u >> 16) & 1u);
    return (unsigned short)(r >> 16);
}

// ---------------------------------------------------------------------------
// K1: ref3d = sigmoid(query_table @ ref_W + ref_b); project through lidar2img.
// ---------------------------------------------------------------------------
__global__ void ref_grid_kernel(const float* __restrict__ qt,
                                const float* __restrict__ refW,
                                const float* __restrict__ refb,
                                const float* __restrict__ l2i,
                                float* __restrict__ gridbuf,
                                float* __restrict__ out_ref3d) {
    int q = blockIdx.x;
    int t = threadIdx.x;  // 0..63
    float s0 = 0.f, s1 = 0.f, s2 = 0.f;
    for (int i = t; i < En; i += 64) {
        float a = qt[q * En + i];
        s0 += a * refW[i * 3 + 0];
        s1 += a * refW[i * 3 + 1];
        s2 += a * refW[i * 3 + 2];
    }
    for (int off = 32; off > 0; off >>= 1) {
        s0 += __shfl_down(s0, off);
        s1 += __shfl_down(s1, off);
        s2 += __shfl_down(s2, off);
    }
    __shared__ float r3[3];
    if (t == 0) {
        float v0 = 1.f / (1.f + expf(-(s0 + refb[0])));
        float v1 = 1.f / (1.f + expf(-(s1 + refb[1])));
        float v2 = 1.f / (1.f + expf(-(s2 + refb[2])));
        r3[0] = v0; r3[1] = v1; r3[2] = v2;
        out_ref3d[(size_t)(0 * Qn + q) * 3 + 0] = v0;
        out_ref3d[(size_t)(0 * Qn + q) * 3 + 1] = v1;
        out_ref3d[(size_t)(0 * Qn + q) * 3 + 2] = v2;
        out_ref3d[(size_t)(1 * Qn + q) * 3 + 0] = v0;
        out_ref3d[(size_t)(1 * Qn + q) * 3 + 1] = v1;
        out_ref3d[(size_t)(1 * Qn + q) * 3 + 2] = v2;
    }
    __syncthreads();
    if (t < Bv * Ncam) {
        int b = t / Ncam, n = t % Ncam;
        const float* M = l2i + (size_t)(b * Ncam + n) * 16;
        float p0 = M[0] * r3[0] + M[1] * r3[1] + M[2]  * r3[2] + M[3];
        float p1 = M[4] * r3[0] + M[5] * r3[1] + M[6]  * r3[2] + M[7];
        float z  = M[8] * r3[0] + M[9] * r3[1] + M[10] * r3[2] + M[11];
        float denom = fabsf(z) + 1e-5f;
        float px = p0 / denom, py = p1 / denom;
        float gx = px / (float)(Ww - 1) * 2.f - 1.f;
        float gy = py / (float)(Hh - 1) * 2.f - 1.f;
        bool zm = z > 1e-5f;
        bool valid = (gx > -1.f) && (gx < 1.f) && (gy > -1.f) && (gy < 1.f);
        float* g = gridbuf + ((size_t)(b * Ncam + n) * Qn + q) * 3;
        g[0] = gx; g[1] = gy; g[2] = (zm && valid) ? 1.f : 0.f;
    }
}

// ---------------------------------------------------------------------------
// K2: transpose feats (BN, C, H, W) -> (BN, H, W, C).
// ---------------------------------------------------------------------------
__global__ void transpose_kernel(const float* __restrict__ in,
                                 float* __restrict__ outp) {
    __shared__ float tile[32][33];
    int mh = blockIdx.z;
    int m = mh / Hh, h = mh % Hh;
    int w0 = blockIdx.x * 32, c0 = blockIdx.y * 32;
    int tx = threadIdx.x, ty = threadIdx.y;  // 32, 8
    for (int i = 0; i < 32; i += 8) {
        int c = c0 + ty + i, w = w0 + tx;
        if (w < Ww)
            tile[ty + i][tx] = in[(((size_t)m * Cch + c) * Hh + h) * Ww + w];
    }
    __syncthreads();
    for (int i = 0; i < 32; i += 8) {
        int w = w0 + ty + i, c = c0 + tx;
        if (w < Ww)
            outp[(((size_t)m * Hh + h) * Ww + w) * Cch + c] = tile[tx][ty + i];
    }
}

// ---------------------------------------------------------------------------
// K3: bilinear sample + masked mean + add query embedding.
// ---------------------------------------------------------------------------
__device__ __forceinline__ float corner_val(const float* __restrict__ base,
                                            int xi, int yi, int c) {
    if (xi < 0 || xi >= Ww || yi < 0 || yi >= Hh) return 0.f;
    return base[((size_t)yi * Ww + xi) * Cch + c];
}

__global__ void sample_kernel(const float* __restrict__ featsT,
                              const float* __restrict__ gridbuf,
                              const float* __restrict__ qt,
                              float* __restrict__ xbuf) {
    int bq = blockIdx.x;
    int b = bq / Qn, q = bq % Qn;
    int c = threadIdx.x;
    float acc = 0.f, cnt = 0.f;
    for (int n = 0; n < Ncam; n++) {
        const float* g = gridbuf + ((size_t)(b * Ncam + n) * Qn + q) * 3;
        float gx = g[0], gy = g[1], msk = g[2];
        if (msk > 0.5f) {
            cnt += 1.f;
            float x = ((gx + 1.f) * (float)Ww - 1.f) * 0.5f;
            float y = ((gy + 1.f) * (float)Hh - 1.f) * 0.5f;
            float x0f = floorf(x), y0f = floorf(y);
            int x0 = (int)x0f, y0 = (int)y0f;
            float wx1 = x - x0f, wx0 = 1.f - wx1;
            float wy1 = y - y0f, wy0 = 1.f - wy1;
            int m = b * Ncam + n;
            const float* base = featsT + (size_t)m * Hh * Ww * Cch;
            acc += corner_val(base, x0,     y0,     c) * (wx0 * wy0);
            acc += corner_val(base, x0 + 1, y0,     c) * (wx1 * wy0);
            acc += corner_val(base, x0,     y0 + 1, c) * (wx0 * wy1);
            acc += corner_val(base, x0 + 1, y0 + 1, c) * (wx1 * wy1);
        }
    }
    float tgt = acc / fmaxf(cnt, 1.f);
    xbuf[(size_t)bq * En + c] = qt[q * En + c] + tgt;
}

// ---------------------------------------------------------------------------
// K4: generic fp32 GEMM  C[M,N] = A[M,K] @ W[K,N] + bias[N]
// ---------------------------------------------------------------------------
__device__ __forceinline__ void gemm_body(const float* __restrict__ A,
                                          const float* __restrict__ Wm,
                                          const float* __restrict__ bias,
                                          float* __restrict__ Cout,
                                          int M, int K, int Nn,
                                          int m0, int n0) {
    __shared__ float As[16][65];
    __shared__ float Bs[16][65];
    int t = threadIdx.x;
    int tx = t % 16, ty = t / 16;
    float acc[4][4] = {};
    for (int k0 = 0; k0 < K; k0 += 16) {
        {
            int kk = t % 16, mb = t / 16;
            for (int i = 0; i < 4; i++) {
                int mm = mb + 16 * i;
                int mg = m0 + mm;
                As[kk][mm] = (mg < M) ? A[(size_t)mg * K + k0 + kk] : 0.f;
            }
        }
        {
            int nn = t % 64, kb = t / 64;
            for (int i = 0; i < 4; i++) {
                int kk = kb + 4 * i;
                Bs[kk][nn] = Wm[(size_t)(k0 + kk) * Nn + n0 + nn];
            }
        }
        __syncthreads();
        for (int kk = 0; kk < 16; kk++) {
            float a[4], bb[4];
            #pragma unroll
            for (int i = 0; i < 4; i++) a[i] = As[kk][ty * 4 + i];
            #pragma unroll
            for (int j = 0; j < 4; j++) bb[j] = Bs[kk][tx * 4 + j];
            #pragma unroll
            for (int i = 0; i < 4; i++)
                #pragma unroll
                for (int j = 0; j < 4; j++) acc[i][j] += a[i] * bb[j];
        }
        __syncthreads();
    }
    for (int i = 0; i < 4; i++) {
        int m = m0 + ty * 4 + i;
        if (m >= M) continue;
        for (int j = 0; j < 4; j++) {
            int n = n0 + tx * 4 + j;
            Cout[(size_t)m * Nn + n] = acc[i][j] + bias[n];
        }
    }
}

__global__ void gemm_bias_kernel(const float* __restrict__ A,
                                 const float* __restrict__ Wm,
                                 const float* __restrict__ bias,
                                 float* __restrict__ Cout,
                                 int M, int K, int Nn) {
    gemm_body(A, Wm, bias, Cout, M, K, Nn, blockIdx.x * 64, blockIdx.y * 64);
}

__global__ void qkv_gemm_kernel(const float* __restrict__ A,
                                const float* __restrict__ Wq, const float* __restrict__ bq,
                                const float* __restrict__ Wk, const float* __restrict__ bk,
                                const float* __restrict__ Wv, const float* __restrict__ bv,
                                float* __restrict__ qo, float* __restrict__ ko,
                                float* __restrict__ vo, int M) {
    const float* Wm; const float* bias; float* Cout;
    if (blockIdx.z == 0)      { Wm = Wq; bias = bq; Cout = qo; }
    else if (blockIdx.z == 1) { Wm = Wk; bias = bk; Cout = ko; }
    else                      { Wm = Wv; bias = bv; Cout = vo; }
    gemm_body(A, Wm, bias, Cout, M, En, En, blockIdx.x * 64, blockIdx.y * 64);
}

// ---------------------------------------------------------------------------
// K5: MFMA flash attention. Block = 4 waves, 64 q-rows (16/wave), one (b,h).
// bf16 inputs to mfma_f32_16x16x32_bf16, fp32 accumulate, online softmax.
// A-frag: A[m=lane&15][k=quad*8+j]. B-frag: B[k=quad*8+j][n=lane&15].
// C/D: row=quad*4+reg, col=lane&15.  (m89/m91/m120-verified layouts)
// ---------------------------------------------------------------------------
static constexpr int FTQ = 64;   // q rows per block
static constexpr int FTK = 64;   // keys per tile

__global__ __launch_bounds__(256)
void flash_attn_mfma_kernel(const float* __restrict__ qbuf,
                            const float* __restrict__ kbuf,
                            const float* __restrict__ vbuf,
                            float* __restrict__ obuf) {
    __shared__ unsigned short Ks[FTK][40];      // [n][k] bf16, pad to 40
    __shared__ unsigned short Vt[HD][72];       // [d][k] bf16, pad to 72
    __shared__ unsigned short Ps[4][16][72];    // per-wave P in A-layout rows

    int bh = blockIdx.y;
    int b = bh / NH, h = bh % NH;
    int m0 = blockIdx.x * FTQ;
    int t = threadIdx.x;
    int wave = t >> 6, lane = t & 63;
    int quad = lane >> 4, col = lane & 15;

    const float scale = 0.17677669529663687f;  // 1/sqrt(32), folded into Q

    union { bf16x8 v; unsigned short u[8]; } qf;
    {
        int qrow = m0 + wave * 16 + col;
        if (qrow < Qn) {
            const float* qp = qbuf + ((size_t)b * Qn + qrow) * En + h * HD + quad * 8;
            #pragma unroll
            for (int j = 0; j < 8; j++) qf.u[j] = f2bf(qp[j] * scale);
        } else {
            #pragma unroll
            for (int j = 0; j < 8; j++) qf.u[j] = 0;
        }
    }

    f32x4 o0 = {0.f, 0.f, 0.f, 0.f};
    f32x4 o1 = {0.f, 0.f, 0.f, 0.f};
    float mrow[4] = {-3e38f, -3e38f, -3e38f, -3e38f};
    float lrow[4] = {0.f, 0.f, 0.f, 0.f};

    int nstage = t >> 2;          // 0..63: staging row
    int kk4 = (t & 3) * 8;        // staging k-offset

    for (int n0 = 0; n0 < Qn; n0 += FTK) {
        // ---- stage K (row-major) and V (transposed) tiles as bf16 ----
        {
            int ng = n0 + nstage;
            union { bf16x8 v; unsigned short u[8]; } kb, vb;
            if (ng < Qn) {
                const float* kp = kbuf + ((size_t)b * Qn + ng) * En + h * HD + kk4;
                const float* vp = vbuf + ((size_t)b * Qn + ng) * En + h * HD + kk4;
                #pragma unroll
                for (int j = 0; j < 8; j++) { kb.u[j] = f2bf(kp[j]); vb.u[j] = f2bf(vp[j]); }
            } else {
                #pragma unroll
                for (int j = 0; j < 8; j++) { kb.u[j] = 0; vb.u[j] = 0; }
            }
            *(bf16x8*)&Ks[nstage][kk4] = kb.v;
            #pragma unroll
            for (int j = 0; j < 8; j++) Vt[kk4 + j][nstage] = vb.u[j];
        }
        __syncthreads();

        // ---- S tile: 16 rows x 64 cols via 4 MFMAs ----
        f32x4 S[4];
        #pragma unroll
        for (int c = 0; c < 4; c++) {
            bf16x8 kf = *(const bf16x8*)&Ks[c * 16 + col][quad * 8];
            f32x4 z = {0.f, 0.f, 0.f, 0.f};
            S[c] = __builtin_amdgcn_mfma_f32_16x16x32_bf16(qf.v, kf, z, 0, 0, 0);
        }
        if (n0 + FTK > Qn) {   // mask invalid keys (last tile)
            #pragma unroll
            for (int c = 0; c < 4; c++) {
                if (n0 + c * 16 + col >= Qn) {
                    S[c][0] = -3e38f; S[c][1] = -3e38f; S[c][2] = -3e38f; S[c][3] = -3e38f;
                }
            }
        }

        // ---- online softmax per row (row = quad*4+r) ----
        float p[4][4];
        #pragma unroll
        for (int r = 0; r < 4; r++) {
            float mx = fmaxf(fmaxf(S[0][r], S[1][r]), fmaxf(S[2][r], S[3][r]));
            #pragma unroll
            for (int off = 8; off >= 1; off >>= 1)
                mx = fmaxf(mx, __shfl_xor(mx, off, 64));
            float mnew = fmaxf(mrow[r], mx);
            float alpha = __expf(mrow[r] - mnew);
            mrow[r] = mnew;
            float rs = 0.f;
            #pragma unroll
            for (int c = 0; c < 4; c++) {
                float pv = __expf(S[c][r] - mnew);
                p[c][r] = pv;
                rs += pv;
            }
            #pragma unroll
            for (int off = 8; off >= 1; off >>= 1)
                rs += __shfl_xor(rs, off, 64);
            lrow[r] = lrow[r] * alpha + rs;
            o0[r] *= alpha;
            o1[r] *= alpha;
        }

        // ---- P: C-layout -> A-layout via per-wave LDS round trip ----
        #pragma unroll
        for (int c = 0; c < 4; c++)
            #pragma unroll
            for (int r = 0; r < 4; r++)
                Ps[wave][quad * 4 + r][c * 16 + col] = f2bf(p[c][r]);

        // ---- PV: O += P(16x64) @ V(64x32), 2 k-chunks x 2 d-chunks ----
        #pragma unroll
        for (int kc = 0; kc < 2; kc++) {
            bf16x8 pf = *(const bf16x8*)&Ps[wave][col][kc * 32 + quad * 8];
            bf16x8 v0 = *(const bf16x8*)&Vt[col][kc * 32 + quad * 8];
            bf16x8 v1 = *(const bf16x8*)&Vt[16 + col][kc * 32 + quad * 8];
            o0 = __builtin_amdgcn_mfma_f32_16x16x32_bf16(pf, v0, o0, 0, 0, 0);
            o1 = __builtin_amdgcn_mfma_f32_16x16x32_bf16(pf, v1, o1, 0, 0, 0);
        }
        __syncthreads();
    }

    #pragma unroll
    for (int r = 0; r < 4; r++) {
        int q = m0 + wave * 16 + quad * 4 + r;
        if (q < Qn) {
            float inv = 1.f / lrow[r];
            float* op = obuf + ((size_t)b * Qn + q) * En + h * HD;
            op[col]      = o0[r] * inv;
            op[16 + col] = o1[r] * inv;
        }
    }
}

// ---------------------------------------------------------------------------
// K6: LN + box head. One block per (b,q), 256 threads.
// ---------------------------------------------------------------------------
__global__ void ln_box_kernel(const float* __restrict__ x2,
                              const float* __restrict__ ln_g,
                              const float* __restrict__ ln_b,
                              const float* __restrict__ boxW,
                              const float* __restrict__ boxb,
                              float* __restrict__ outp) {
    __shared__ float red[256];
    __shared__ float yrow[En];
    __shared__ float pbox[16][10];
    int bq = blockIdx.x;
    int t = threadIdx.x;
    float acc = x2[(size_t)bq * En + t];
    red[t] = acc; __syncthreads();
    for (int s = 128; s > 0; s >>= 1) {
        if (t < s) red[t] += red[t + s];
        __syncthreads();
    }
    float mu = red[0] / (float)En;
    __syncthreads();
    float dx = acc - mu;
    red[t] = dx * dx; __syncthreads();
    for (int s = 128; s > 0; s >>= 1) {
        if (t < s) red[t] += red[t + s];
        __syncthreads();
    }
    float var = red[0] / (float)En;
    float y = dx * rsqrtf(var + 1e-5f) * ln_g[t] + ln_b[t];
    yrow[t] = y;
    __syncthreads();
    if (t < 160) {
        int j = t % 10, ch = t / 10;
        float p = 0.f;
        for (int k = ch * 16; k < ch * 16 + 16; k++)
            p += yrow[k] * boxW[(size_t)k * 10 + j];
        pbox[ch][j] = p;
    }
    __syncthreads();
    if (t < 10) {
        float o = boxb[t];
        for (int ch = 0; ch < 16; ch++) o += pbox[ch][t];
        outp[(size_t)bq * 10 + t] = o;
    }
}

// ---------------------------------------------------------------------------
extern "C" void kernel_launch(void* const* d_in, const int* in_sizes, int n_in,
                              void* d_out, int out_size, void* d_ws, size_t ws_size,
                              hipStream_t stream) {
    const float* image_features = (const float*)d_in[0];
    const float* lidar2img      = (const float*)d_in[1];
    const float* query_table    = (const float*)d_in[2];
    const float* ref_W          = (const float*)d_in[3];
    const float* ref_b          = (const float*)d_in[4];
    const float* Wq             = (const float*)d_in[5];
    const float* bq             = (const float*)d_in[6];
    const float* Wk             = (const float*)d_in[7];
    const float* bk             = (const float*)d_in[8];
    const float* Wv             = (const float*)d_in[9];
    const float* bv             = (const float*)d_in[10];
    const float* Wo             = (const float*)d_in[11];
    const float* bo             = (const float*)d_in[12];
    const float* ln_g           = (const float*)d_in[13];
    const float* ln_b           = (const float*)d_in[14];
    const float* box_W          = (const float*)d_in[15];
    const float* box_b          = (const float*)d_in[16];
    float* out = (float*)d_out;

    float* ws = (float*)d_ws;
    size_t off = 0;
    float* gridbuf = ws + off; off += (size_t)Bv * Ncam * Qn * 3;
    float* featsT  = ws + off; off += (size_t)Bv * Ncam * Hh * Ww * Cch;
    float* xbuf    = ws + off; off += (size_t)Bv * Qn * En;
    float* qbuf    = ws + off; off += (size_t)Bv * Qn * En;
    float* kbuf    = ws + off; off += (size_t)Bv * Qn * En;
    float* vbuf    = ws + off; off += (size_t)Bv * Qn * En;
    float* Obuf    = ws + off; off += (size_t)Bv * Qn * En;   // (b,q,E)
    float* x2buf   = ws + off; off += (size_t)Bv * Qn * En;

    float* out_ref3d = out + (size_t)Bv * Qn * 10;

    // K1: ref points + projection grid
    hipLaunchKernelGGL(ref_grid_kernel, dim3(Qn), dim3(64), 0, stream,
                       query_table, ref_W, ref_b, lidar2img, gridbuf, out_ref3d);

    // K2: transpose features to channel-last
    hipLaunchKernelGGL(transpose_kernel, dim3(4, 8, Bv * Ncam * Hh), dim3(32, 8),
                       0, stream, image_features, featsT);

    // K3: bilinear sample + masked mean + add query embedding
    hipLaunchKernelGGL(sample_kernel, dim3(Bv * Qn), dim3(256), 0, stream,
                       featsT, gridbuf, query_table, xbuf);

    // K4: q/k/v projections (single launch, z = 3)
    int M = Bv * Qn;
    hipLaunchKernelGGL(qkv_gemm_kernel, dim3((M + 63) / 64, En / 64, 3), dim3(256),
                       0, stream, xbuf, Wq, bq, Wk, bk, Wv, bv, qbuf, kbuf, vbuf, M);

    // K5: MFMA flash attention
    hipLaunchKernelGGL(flash_attn_mfma_kernel,
                       dim3((Qn + FTQ - 1) / FTQ, Bv * NH), dim3(256), 0, stream,
                       qbuf, kbuf, vbuf, Obuf);

    // K6: o @ Wo + bo
    hipLaunchKernelGGL(gemm_bias_kernel, dim3((M + 63) / 64, En / 64), dim3(256),
                       0, stream, Obuf, Wo, bo, x2buf, M, En, En);

    // K7: LN + box head
    hipLaunchKernelGGL(ln_box_kernel, dim3(Bv * Qn), dim3(256), 0, stream,
                       x2buf, ln_g, ln_b, box_W, box_b, out);
}

// Round 4
// 185.024 us; speedup vs baseline: 4.4938x; 1.4616x over previous
//
#include <hip/hip_runtime.h>
#include <math.h>

// Problem constants
static constexpr int Bv  = 2;
static constexpr int Ncam= 6;
static constexpr int Cch = 256;
static constexpr int Hh  = 56;
static constexpr int Ww  = 100;
static constexpr int Pn  = Hh * Ww;  // 5600 flat pixels
static constexpr int Qn  = 900;
static constexpr int En  = 256;
static constexpr int NH  = 8;
static constexpr int HD  = 32;   // E / NH

typedef _Float16 f16x8 __attribute__((ext_vector_type(8)));
typedef _Float16 f16x4 __attribute__((ext_vector_type(4)));
typedef float    f32x4 __attribute__((ext_vector_type(4)));

// ---------------------------------------------------------------------------
// K0: pack weights W[K=256][N=256] fp32 -> Wt[N][K] f16 (4 matrices).
// ---------------------------------------------------------------------------
__global__ void wpack_kernel(const float* __restrict__ W0,
                             const float* __restrict__ W1,
                             const float* __restrict__ W2,
                             const float* __restrict__ W3,
                             _Float16* __restrict__ outp) {
    __shared__ float tile[32][33];
    int z = blockIdx.z;
    const float* src = (z == 0) ? W0 : (z == 1) ? W1 : (z == 2) ? W2 : W3;
    int k0 = blockIdx.x * 32, n0 = blockIdx.y * 32;
    int tx = threadIdx.x, ty = threadIdx.y;  // 32, 8
    for (int i = 0; i < 32; i += 8)
        tile[ty + i][tx] = src[(size_t)(k0 + ty + i) * 256 + n0 + tx];
    __syncthreads();
    _Float16* dst = outp + (size_t)z * 256 * 256;
    for (int i = 0; i < 32; i += 8)
        dst[(size_t)(n0 + ty + i) * 256 + k0 + tx] = (_Float16)tile[tx][ty + i];
}

// ---------------------------------------------------------------------------
// K1: ref3d = sigmoid(query_table @ ref_W + ref_b); project through lidar2img.
// ---------------------------------------------------------------------------
__global__ void ref_grid_kernel(const float* __restrict__ qt,
                                const float* __restrict__ refW,
                                const float* __restrict__ refb,
                                const float* __restrict__ l2i,
                                float* __restrict__ gridbuf,
                                float* __restrict__ out_ref3d) {
    int q = blockIdx.x;
    int t = threadIdx.x;  // 0..63
    float s0 = 0.f, s1 = 0.f, s2 = 0.f;
    for (int i = t; i < En; i += 64) {
        float a = qt[q * En + i];
        s0 += a * refW[i * 3 + 0];
        s1 += a * refW[i * 3 + 1];
        s2 += a * refW[i * 3 + 2];
    }
    for (int off = 32; off > 0; off >>= 1) {
        s0 += __shfl_down(s0, off);
        s1 += __shfl_down(s1, off);
        s2 += __shfl_down(s2, off);
    }
    __shared__ float r3[3];
    if (t == 0) {
        float v0 = 1.f / (1.f + expf(-(s0 + refb[0])));
        float v1 = 1.f / (1.f + expf(-(s1 + refb[1])));
        float v2 = 1.f / (1.f + expf(-(s2 + refb[2])));
        r3[0] = v0; r3[1] = v1; r3[2] = v2;
        out_ref3d[(size_t)(0 * Qn + q) * 3 + 0] = v0;
        out_ref3d[(size_t)(0 * Qn + q) * 3 + 1] = v1;
        out_ref3d[(size_t)(0 * Qn + q) * 3 + 2] = v2;
        out_ref3d[(size_t)(1 * Qn + q) * 3 + 0] = v0;
        out_ref3d[(size_t)(1 * Qn + q) * 3 + 1] = v1;
        out_ref3d[(size_t)(1 * Qn + q) * 3 + 2] = v2;
    }
    __syncthreads();
    if (t < Bv * Ncam) {
        int b = t / Ncam, n = t % Ncam;
        const float* M = l2i + (size_t)(b * Ncam + n) * 16;
        float p0 = M[0] * r3[0] + M[1] * r3[1] + M[2]  * r3[2] + M[3];
        float p1 = M[4] * r3[0] + M[5] * r3[1] + M[6]  * r3[2] + M[7];
        float z  = M[8] * r3[0] + M[9] * r3[1] + M[10] * r3[2] + M[11];
        float denom = fabsf(z) + 1e-5f;
        float px = p0 / denom, py = p1 / denom;
        float gx = px / (float)(Ww - 1) * 2.f - 1.f;
        float gy = py / (float)(Hh - 1) * 2.f - 1.f;
        bool zm = z > 1e-5f;
        bool valid = (gx > -1.f) && (gx < 1.f) && (gy > -1.f) && (gy < 1.f);
        float* g = gridbuf + ((size_t)(b * Ncam + n) * Qn + q) * 3;
        g[0] = gx; g[1] = gy; g[2] = (zm && valid) ? 1.f : 0.f;
    }
}

// ---------------------------------------------------------------------------
// K2: feats (BN, C, P) fp32 -> featsT (BN, P, C) f16. Tile 32c x 128p.
// float4 loads, b64 LDS writes, 8B global stores.
// ---------------------------------------------------------------------------
__global__ __launch_bounds__(256)
void feat_pack_kernel(const float* __restrict__ in, _Float16* __restrict__ outp) {
    __shared__ _Float16 tile[32][132];
    int m = blockIdx.z;
    int p0 = blockIdx.x * 128, c0 = blockIdx.y * 32;
    int t = threadIdx.x;
    {
        int p4 = (t & 31) * 4;     // local p, x4
        int cc0 = t >> 5;          // 0..7
        for (int i = 0; i < 4; i++) {
            int cc = cc0 + i * 8;
            int p = p0 + p4;
            if (p < Pn) {
                float4 v = *(const float4*)&in[((size_t)m * Cch + c0 + cc) * Pn + p];
                f16x4 h = {(_Float16)v.x, (_Float16)v.y, (_Float16)v.z, (_Float16)v.w};
                *(f16x4*)&tile[cc][p4] = h;
            }
        }
    }
    __syncthreads();
    {
        int cg = (t & 7) * 4;      // c offset, x4
        int pr = t >> 3;           // 0..31
        for (int i = 0; i < 4; i++) {
            int pl = pr + i * 32;
            int p = p0 + pl;
            if (p < Pn) {
                f16x4 h = {tile[0][0], tile[0][0], tile[0][0], tile[0][0]};
                h.x = tile[cg + 0][pl];
                h.y = tile[cg + 1][pl];
                h.z = tile[cg + 2][pl];
                h.w = tile[cg + 3][pl];
                *(f16x4*)&outp[((size_t)m * Pn + p) * Cch + c0 + cg] = h;
            }
        }
    }
}

// ---------------------------------------------------------------------------
// K3: bilinear sample (f16 feats) + masked mean + add query embedding -> f16 x.
// ---------------------------------------------------------------------------
__device__ __forceinline__ float corner_val(const _Float16* __restrict__ base,
                                            int xi, int yi, int c) {
    if (xi < 0 || xi >= Ww || yi < 0 || yi >= Hh) return 0.f;
    return (float)base[((size_t)yi * Ww + xi) * Cch + c];
}

__global__ void sample_kernel(const _Float16* __restrict__ featsT,
                              const float* __restrict__ gridbuf,
                              const float* __restrict__ qt,
                              _Float16* __restrict__ xbuf) {
    int bq = blockIdx.x;
    int b = bq / Qn, q = bq % Qn;
    int c = threadIdx.x;
    float acc = 0.f, cnt = 0.f;
    for (int n = 0; n < Ncam; n++) {
        const float* g = gridbuf + ((size_t)(b * Ncam + n) * Qn + q) * 3;
        float gx = g[0], gy = g[1], msk = g[2];
        if (msk > 0.5f) {
            cnt += 1.f;
            float x = ((gx + 1.f) * (float)Ww - 1.f) * 0.5f;
            float y = ((gy + 1.f) * (float)Hh - 1.f) * 0.5f;
            float x0f = floorf(x), y0f = floorf(y);
            int x0 = (int)x0f, y0 = (int)y0f;
            float wx1 = x - x0f, wx0 = 1.f - wx1;
            float wy1 = y - y0f, wy0 = 1.f - wy1;
            int m = b * Ncam + n;
            const _Float16* base = featsT + (size_t)m * Pn * Cch;
            acc += corner_val(base, x0,     y0,     c) * (wx0 * wy0);
            acc += corner_val(base, x0 + 1, y0,     c) * (wx1 * wy0);
            acc += corner_val(base, x0,     y0 + 1, c) * (wx0 * wy1);
            acc += corner_val(base, x0 + 1, y0 + 1, c) * (wx1 * wy1);
        }
    }
    float tgt = acc / fmaxf(cnt, 1.f);
    xbuf[(size_t)bq * En + c] = (_Float16)(qt[q * En + c] + tgt);
}

// ---------------------------------------------------------------------------
// K4: MFMA f16 GEMM body: C[M,256] = A[M,256] @ W + bias. Wt is [N][K] f16.
// Block: 256 thr = 4 waves; tile M=64 (16 rows/wave), N=64; K=256 unrolled.
// A-frag: A[m=lane&15][k=quad*8+j]; B-frag from Wt rows (k-contiguous).
// C/D: row=quad*4+r, col=lane&15.
// ---------------------------------------------------------------------------
__device__ __forceinline__ void mfma_gemm_body(const _Float16* __restrict__ A,
                                               const _Float16* __restrict__ Wt,
                                               const float* __restrict__ bias,
                                               _Float16* __restrict__ Cf16,
                                               float* __restrict__ Cf32,
                                               int M, int m0, int n0) {
    __shared__ _Float16 Ws[64][264];
    int t = threadIdx.x;
    int wave = t >> 6, lane = t & 63, quad = lane >> 4, col = lane & 15;
    // stage Wt tile [64 n][256 k]
    {
        int row = t >> 5;          // 0..7
        int off = (t & 31) * 8;    // 0..248
        for (int i = 0; i < 8; i++)
            *(f16x8*)&Ws[row + i * 8][off] =
                *(const f16x8*)&Wt[(size_t)(n0 + row + i * 8) * 256 + off];
    }
    // A fragments (held in regs for all 8 k-chunks)
    f16x8 af[8];
    int mrow = m0 + wave * 16 + col;
    if (mrow < M) {
        const _Float16* ap = A + (size_t)mrow * 256 + quad * 8;
        #pragma unroll
        for (int kc = 0; kc < 8; kc++) af[kc] = *(const f16x8*)(ap + kc * 32);
    } else {
        #pragma unroll
        for (int kc = 0; kc < 8; kc++)
            #pragma unroll
            for (int j = 0; j < 8; j++) af[kc][j] = (_Float16)0.f;
    }
    __syncthreads();
    f32x4 acc[4];
    #pragma unroll
    for (int nt = 0; nt < 4; nt++) { acc[nt][0]=0.f; acc[nt][1]=0.f; acc[nt][2]=0.f; acc[nt][3]=0.f; }
    #pragma unroll
    for (int nt = 0; nt < 4; nt++)
        #pragma unroll
        for (int kc = 0; kc < 8; kc++) {
            f16x8 bf = *(const f16x8*)&Ws[nt * 16 + col][kc * 32 + quad * 8];
            acc[nt] = __builtin_amdgcn_mfma_f32_16x16x32_f16(af[kc], bf, acc[nt], 0, 0, 0);
        }
    // epilogue
    #pragma unroll
    for (int nt = 0; nt < 4; nt++) {
        int n = n0 + nt * 16 + col;
        float bv = bias[n];
        #pragma unroll
        for (int r = 0; r < 4; r++) {
            int m = m0 + wave * 16 + quad * 4 + r;
            if (m < M) {
                float v = acc[nt][r] + bv;
                if (Cf16) Cf16[(size_t)m * 256 + n] = (_Float16)v;
                else      Cf32[(size_t)m * 256 + n] = v;
            }
        }
    }
}

// Fused q/k/v projections (z selects).
__global__ __launch_bounds__(256)
void qkv_mfma_kernel(const _Float16* __restrict__ A,
                     const _Float16* __restrict__ Wtall,  // [4][256][256]: q,k,v,o
                     const float* __restrict__ bq, const float* __restrict__ bk,
                     const float* __restrict__ bv,
                     _Float16* __restrict__ qo, _Float16* __restrict__ ko,
                     _Float16* __restrict__ vo, int M) {
    const _Float16* Wt; const float* bias; _Float16* out;
    if (blockIdx.z == 0)      { Wt = Wtall;               bias = bq; out = qo; }
    else if (blockIdx.z == 1) { Wt = Wtall + 256 * 256;   bias = bk; out = ko; }
    else                      { Wt = Wtall + 2 * 256 * 256; bias = bv; out = vo; }
    mfma_gemm_body(A, Wt, bias, out, nullptr, M, blockIdx.x * 64, blockIdx.y * 64);
}

// Wo projection (fp32 out).
__global__ __launch_bounds__(256)
void wo_mfma_kernel(const _Float16* __restrict__ A,
                    const _Float16* __restrict__ Wtall,
                    const float* __restrict__ bo,
                    float* __restrict__ x2, int M) {
    mfma_gemm_body(A, Wtall + 3 * 256 * 256, bo, nullptr, x2, M,
                   blockIdx.x * 64, blockIdx.y * 64);
}

// ---------------------------------------------------------------------------
// K5: MFMA f16 flash attention. Block = 4 waves, 64 q-rows, one (b,h).
// ---------------------------------------------------------------------------
static constexpr int FTQ = 64;   // q rows per block
static constexpr int FTK = 64;   // keys per tile

__global__ __launch_bounds__(256)
void flash_attn_mfma_kernel(const _Float16* __restrict__ qbuf,
                            const _Float16* __restrict__ kbuf,
                            const _Float16* __restrict__ vbuf,
                            _Float16* __restrict__ obuf) {
    __shared__ _Float16 Ks[FTK][40];      // [n][k], pad 40
    __shared__ _Float16 Vt[HD][72];       // [d][k], pad 72
    __shared__ _Float16 Ps[4][16][72];    // per-wave P in A-layout

    int bh = blockIdx.y;
    int b = bh / NH, h = bh % NH;
    int m0 = blockIdx.x * FTQ;
    int t = threadIdx.x;
    int wave = t >> 6, lane = t & 63;
    int quad = lane >> 4, col = lane & 15;

    const float scale = 0.17677669529663687f;  // 1/sqrt(32), applied to S

    f16x8 qf;
    {
        int qrow = m0 + wave * 16 + col;
        if (qrow < Qn) {
            qf = *(const f16x8*)(qbuf + ((size_t)b * Qn + qrow) * En + h * HD + quad * 8);
        } else {
            #pragma unroll
            for (int j = 0; j < 8; j++) qf[j] = (_Float16)0.f;
        }
    }

    f32x4 o0 = {0.f, 0.f, 0.f, 0.f};
    f32x4 o1 = {0.f, 0.f, 0.f, 0.f};
    float mrow[4] = {-3e38f, -3e38f, -3e38f, -3e38f};
    float lrow[4] = {0.f, 0.f, 0.f, 0.f};

    int nstage = t >> 2;          // 0..63: staging row
    int kk4 = (t & 3) * 8;        // staging k-offset

    for (int n0 = 0; n0 < Qn; n0 += FTK) {
        {   // stage K (row-major) and V (transposed)
            int ng = n0 + nstage;
            f16x8 kb, vb;
            if (ng < Qn) {
                kb = *(const f16x8*)(kbuf + ((size_t)b * Qn + ng) * En + h * HD + kk4);
                vb = *(const f16x8*)(vbuf + ((size_t)b * Qn + ng) * En + h * HD + kk4);
            } else {
                #pragma unroll
                for (int j = 0; j < 8; j++) { kb[j] = (_Float16)0.f; vb[j] = (_Float16)0.f; }
            }
            *(f16x8*)&Ks[nstage][kk4] = kb;
            #pragma unroll
            for (int j = 0; j < 8; j++) Vt[kk4 + j][nstage] = vb[j];
        }
        __syncthreads();

        // S tile: 16 rows x 64 cols via 4 MFMAs; scale; mask tail
        f32x4 S[4];
        #pragma unroll
        for (int c = 0; c < 4; c++) {
            f16x8 kf = *(const f16x8*)&Ks[c * 16 + col][quad * 8];
            f32x4 z = {0.f, 0.f, 0.f, 0.f};
            S[c] = __builtin_amdgcn_mfma_f32_16x16x32_f16(qf, kf, z, 0, 0, 0);
            S[c] *= scale;
        }
        if (n0 + FTK > Qn) {
            #pragma unroll
            for (int c = 0; c < 4; c++) {
                if (n0 + c * 16 + col >= Qn) {
                    S[c][0] = -3e38f; S[c][1] = -3e38f; S[c][2] = -3e38f; S[c][3] = -3e38f;
                }
            }
        }

        // online softmax per row (row = quad*4+r)
        float p[4][4];
        #pragma unroll
        for (int r = 0; r < 4; r++) {
            float mx = fmaxf(fmaxf(S[0][r], S[1][r]), fmaxf(S[2][r], S[3][r]));
            #pragma unroll
            for (int off = 8; off >= 1; off >>= 1)
                mx = fmaxf(mx, __shfl_xor(mx, off, 64));
            float mnew = fmaxf(mrow[r], mx);
            float alpha = __expf(mrow[r] - mnew);
            mrow[r] = mnew;
            float rs = 0.f;
            #pragma unroll
            for (int c = 0; c < 4; c++) {
                float pv = __expf(S[c][r] - mnew);
                p[c][r] = pv;
                rs += pv;
            }
            #pragma unroll
            for (int off = 8; off >= 1; off >>= 1)
                rs += __shfl_xor(rs, off, 64);
            lrow[r] = lrow[r] * alpha + rs;
            o0[r] *= alpha;
            o1[r] *= alpha;
        }

        // P: C-layout -> A-layout via per-wave LDS round trip
        #pragma unroll
        for (int c = 0; c < 4; c++)
            #pragma unroll
            for (int r = 0; r < 4; r++)
                Ps[wave][quad * 4 + r][c * 16 + col] = (_Float16)p[c][r];

        // PV: O += P(16x64) @ V(64x32)
        #pragma unroll
        for (int kc = 0; kc < 2; kc++) {
            f16x8 pf = *(const f16x8*)&Ps[wave][col][kc * 32 + quad * 8];
            f16x8 v0 = *(const f16x8*)&Vt[col][kc * 32 + quad * 8];
            f16x8 v1 = *(const f16x8*)&Vt[16 + col][kc * 32 + quad * 8];
            o0 = __builtin_amdgcn_mfma_f32_16x16x32_f16(pf, v0, o0, 0, 0, 0);
            o1 = __builtin_amdgcn_mfma_f32_16x16x32_f16(pf, v1, o1, 0, 0, 0);
        }
        __syncthreads();
    }

    #pragma unroll
    for (int r = 0; r < 4; r++) {
        int q = m0 + wave * 16 + quad * 4 + r;
        if (q < Qn) {
            float inv = 1.f / lrow[r];
            _Float16* op = obuf + ((size_t)b * Qn + q) * En + h * HD;
            op[col]      = (_Float16)(o0[r] * inv);
            op[16 + col] = (_Float16)(o1[r] * inv);
        }
    }
}

// ---------------------------------------------------------------------------
// K6: LN + box head. One block per (b,q), 256 threads.
// ---------------------------------------------------------------------------
__global__ void ln_box_kernel(const float* __restrict__ x2,
                              const float* __restrict__ ln_g,
                              const float* __restrict__ ln_b,
                              const float* __restrict__ boxW,
                              const float* __restrict__ boxb,
                              float* __restrict__ outp) {
    __shared__ float red[256];
    __shared__ float yrow[En];
    __shared__ float pbox[16][10];
    int bq = blockIdx.x;
    int t = threadIdx.x;
    float acc = x2[(size_t)bq * En + t];
    red[t] = acc; __syncthreads();
    for (int s = 128; s > 0; s >>= 1) {
        if (t < s) red[t] += red[t + s];
        __syncthreads();
    }
    float mu = red[0] / (float)En;
    __syncthreads();
    float dx = acc - mu;
    red[t] = dx * dx; __syncthreads();
    for (int s = 128; s > 0; s >>= 1) {
        if (t < s) red[t] += red[t + s];
        __syncthreads();
    }
    float var = red[0] / (float)En;
    float y = dx * rsqrtf(var + 1e-5f) * ln_g[t] + ln_b[t];
    yrow[t] = y;
    __syncthreads();
    if (t < 160) {
        int j = t % 10, ch = t / 10;
        float p = 0.f;
        for (int k = ch * 16; k < ch * 16 + 16; k++)
            p += yrow[k] * boxW[(size_t)k * 10 + j];
        pbox[ch][j] = p;
    }
    __syncthreads();
    if (t < 10) {
        float o = boxb[t];
        for (int ch = 0; ch < 16; ch++) o += pbox[ch][t];
        outp[(size_t)bq * 10 + t] = o;
    }
}

// ---------------------------------------------------------------------------
extern "C" void kernel_launch(void* const* d_in, const int* in_sizes, int n_in,
                              void* d_out, int out_size, void* d_ws, size_t ws_size,
                              hipStream_t stream) {
    const float* image_features = (const float*)d_in[0];
    const float* lidar2img      = (const float*)d_in[1];
    const float* query_table    = (const float*)d_in[2];
    const float* ref_W          = (const float*)d_in[3];
    const float* ref_b          = (const float*)d_in[4];
    const float* Wq             = (const float*)d_in[5];
    const float* bq             = (const float*)d_in[6];
    const float* Wk             = (const float*)d_in[7];
    const float* bk             = (const float*)d_in[8];
    const float* Wv             = (const float*)d_in[9];
    const float* bv             = (const float*)d_in[10];
    const float* Wo             = (const float*)d_in[11];
    const float* bo             = (const float*)d_in[12];
    const float* ln_g           = (const float*)d_in[13];
    const float* ln_b           = (const float*)d_in[14];
    const float* box_W          = (const float*)d_in[15];
    const float* box_b          = (const float*)d_in[16];
    float* out = (float*)d_out;

    char* ws = (char*)d_ws;
    size_t off = 0;
    auto alloc = [&](size_t bytes) { char* p = ws + off; off += (bytes + 255) & ~size_t(255); return p; };
    float*     gridbuf = (float*)    alloc((size_t)Bv * Ncam * Qn * 3 * 4);
    _Float16*  featsT  = (_Float16*) alloc((size_t)Bv * Ncam * Pn * Cch * 2);
    _Float16*  xbuf    = (_Float16*) alloc((size_t)Bv * Qn * En * 2);
    _Float16*  qbuf    = (_Float16*) alloc((size_t)Bv * Qn * En * 2);
    _Float16*  kbuf    = (_Float16*) alloc((size_t)Bv * Qn * En * 2);
    _Float16*  vbuf    = (_Float16*) alloc((size_t)Bv * Qn * En * 2);
    _Float16*  obuf    = (_Float16*) alloc((size_t)Bv * Qn * En * 2);
    float*     x2buf   = (float*)    alloc((size_t)Bv * Qn * En * 4);
    _Float16*  Wtall   = (_Float16*) alloc((size_t)4 * 256 * 256 * 2);

    float* out_ref3d = out + (size_t)Bv * Qn * 10;
    int M = Bv * Qn;  // 1800

    // K0: pack weights (q,k,v,o) -> f16 transposed [N][K]
    hipLaunchKernelGGL(wpack_kernel, dim3(8, 8, 4), dim3(32, 8), 0, stream,
                       Wq, Wk, Wv, Wo, Wtall);

    // K1: ref points + projection grid
    hipLaunchKernelGGL(ref_grid_kernel, dim3(Qn), dim3(64), 0, stream,
                       query_table, ref_W, ref_b, lidar2img, gridbuf, out_ref3d);

    // K2: feature transpose+f16 pack
    hipLaunchKernelGGL(feat_pack_kernel,
                       dim3((Pn + 127) / 128, Cch / 32, Bv * Ncam), dim3(256),
                       0, stream, image_features, featsT);

    // K3: bilinear sample + masked mean + add query embedding
    hipLaunchKernelGGL(sample_kernel, dim3(Bv * Qn), dim3(256), 0, stream,
                       featsT, gridbuf, query_table, xbuf);

    // K4: q/k/v projections (MFMA f16, fused)
    hipLaunchKernelGGL(qkv_mfma_kernel, dim3((M + 63) / 64, En / 64, 3), dim3(256),
                       0, stream, xbuf, Wtall, bq, bk, bv, qbuf, kbuf, vbuf, M);

    // K5: MFMA flash attention
    hipLaunchKernelGGL(flash_attn_mfma_kernel,
                       dim3((Qn + FTQ - 1) / FTQ, Bv * NH), dim3(256), 0, stream,
                       qbuf, kbuf, vbuf, obuf);

    // K6: o @ Wo + bo (MFMA f16, fp32 out)
    hipLaunchKernelGGL(wo_mfma_kernel, dim3((M + 63) / 64, En / 64), dim3(256),
                       0, stream, obuf, Wtall, bo, x2buf, M);

    // K7: LN + box head
    hipLaunchKernelGGL(ln_box_kernel, dim3(Bv * Qn), dim3(256), 0, stream,
                       x2buf, ln_g, ln_b, box_W, box_b, out);
}